// Round 14
// baseline (299.510 us; speedup 1.0000x reference)
//
#include <hip/hip_runtime.h>
#include <hip/hip_bf16.h>

#define IDIM 256
#define GDIM 64
#define ODIM 512
#define KD   (IDIM * GDIM)
#define TILE_SHORTS (512 * 64)
#define TILE_BYTES  (TILE_SHORTS * 2)
#define WS_NEED ((size_t)512 * TILE_SHORTS * 2)   // 32 MB bf16 image

typedef __attribute__((ext_vector_type(8))) short bhalf8;
typedef __attribute__((ext_vector_type(4))) float fvec4;
typedef __attribute__((ext_vector_type(4))) unsigned uvec4;

#define INV2PI 0.15915494309189535f

static __device__ __forceinline__ short bf16b(float v) {
    __hip_bfloat16 hb = __float2bfloat16(v);
    short s; __builtin_memcpy(&s, &hb, 2); return s;
}
static __device__ __forceinline__ unsigned cvtpk(float lo, float hi) {
    unsigned r;
    asm("v_cvt_pk_bf16_f32 %0, %1, %2" : "=v"(r) : "v"(lo), "v"(hi));
    return r;
}

// advance one chain (cos or sin) by two Chebyshev steps
#define ADVP(A,B,C2) do { float _t = __builtin_fmaf((C2),(B),-(A)); (A)=(B); (B)=_t; \
                          _t = __builtin_fmaf((C2),(B),-(A)); (A)=(B); (B)=_t; } while (0)

// ws image, K-permuted [proven R5/R8/R9/R13]: tile b = i*2+h, row o (512),
// slot z*32 + Q*8 + u -> coeff[z][o][i][16Q + 8h + u]; rows 128 B,
// XOR-swizzled 16B granules (^(o&7)<<4).
__global__ void prep_b(const float* __restrict__ coeffs, short* __restrict__ ws) {
    const int b = blockIdx.x;          // 512: i*2+h
    const int i = b >> 1, h = b & 1;
    const int o = threadIdx.x;         // 512
    short* dst = ws + ((size_t)b * 512 + o) * 64;
    const int swz = (o & 7) << 4;
#pragma unroll
    for (int j = 0; j < 8; ++j) {      // granule: z = j>>2, Q = j&3
        const int z = j >> 2, Qq = j & 3;
        const float* src = coeffs + ((size_t)z * ODIM + o) * KD
                         + (size_t)i * GDIM + 16 * Qq + 8 * h;
        fvec4 v0 = ((const fvec4*)src)[0];
        fvec4 v1 = ((const fvec4*)src)[1];
        bhalf8 pk;
#pragma unroll
        for (int u = 0; u < 4; ++u) { pk[u] = bf16b(v0[u]); pk[4 + u] = bf16b(v1[u]); }
        *(bhalf8*)((char*)dst + ((j * 16) ^ swz)) = pk;
    }
}

__global__ void bias_init(const float* __restrict__ bias, float* __restrict__ out) {
    int idx = blockIdx.x * 256 + threadIdx.x;
    fvec4 bv = ((const fvec4*)bias)[idx & 127];
    ((fvec4*)out)[idx] = bv;
}

// Barrier-free direct-from-L2 GEMM. 2048 blocks = 32 mt x 4 ot x 16 ks; per-XCD
// pinning: 8 (ot,ks) groups x 0.5 MB B-slice = 4 MB = one XCD L2. Block 256 thr
// = 4 waves (2x2): wave owns 64 rows x 64 cols (acc[4][4]). NO LDS, NO barriers:
// B fragments load straight from the pre-swizzled ws image into registers,
// double-buffered 2 tiles deep; A in-register Chebyshev (R9-proven sequences);
// x loaded per-lane. Compiler schedules everything; 3 waves/SIMD hide latency.
template<int USE_WS>
__global__ void __launch_bounds__(256, 3)
fkan_gemm(const float* __restrict__ x, const float* __restrict__ coeffs,
          const short* __restrict__ wsb, float* __restrict__ out) {
    const int bx = blockIdx.x;             // 0..2047
    const int xcd = bx & 7, j = bx >> 3;   // j 0..255
    const int lg  = xcd * 8 + (j & 7);     // 0..63 = (ot,ks)
    const int mt  = j >> 3;                // 0..31
    const int ot  = lg >> 4, ks = lg & 15;
    const int row0 = mt * 128, col0 = ot * 128;
    const int i0 = ks * 16;

    const int t = threadIdx.x;
    const int lane = t & 63, wid = t >> 6;
    const int wave_m = wid & 1, wave_n = wid >> 1;   // 2 x 2
    const int kl  = (lane >> 4) * 16;
    const int msk = (lane & 7) << 4;
    const int rA0 = wave_m * 64 + (lane & 15);
    const int cB0 = wave_n * 64 + (lane & 15);
    const float m0f = (float)(16 * (lane >> 4) + 1);

    fvec4 acc[4][4];
#pragma unroll
    for (int a = 0; a < 4; ++a)
#pragma unroll
        for (int b = 0; b < 4; ++b) acc[a][b] = (fvec4)0.0f;

    // per-lane byte offsets of the 8 B fragments within one tile image
    int boff[2][4];
#pragma unroll
    for (int z = 0; z < 2; ++z)
#pragma unroll
        for (int fn = 0; fn < 4; ++fn)
            boff[z][fn] = (cB0 + fn * 16) * 128 + ((z * 64 + kl) ^ msk);

    const char* wsb0 = (const char*)wsb + (size_t)(i0 * 2) * TILE_BYTES
                     + (size_t)col0 * 128;
    const float* xb = x + (size_t)(row0 + rA0) * IDIM + i0;

    bhalf8 bq0[8], bq1[8];   // [z*4+fn], two tiles in flight

    auto loadB = [&](bhalf8* bq, int T) {
        if (USE_WS) {
            const char* tb = wsb0 + (size_t)T * TILE_BYTES;
#pragma unroll
            for (int z = 0; z < 2; ++z)
#pragma unroll
                for (int fn = 0; fn < 4; ++fn)
                    bq[z * 4 + fn] = *(const bhalf8*)(tb + boff[z][fn]);
        } else {
            const int i = i0 + (T >> 1), h = T & 1, Q = lane >> 4;
#pragma unroll
            for (int z = 0; z < 2; ++z)
#pragma unroll
                for (int fn = 0; fn < 4; ++fn) {
                    const float* f = coeffs
                        + ((size_t)z * ODIM + col0 + cB0 + fn * 16) * KD
                        + (size_t)i * GDIM + 16 * Q + 8 * h;
                    fvec4 v0 = ((const fvec4*)f)[0];
                    fvec4 v1 = ((const fvec4*)f)[1];
                    uvec4 u;
                    u[0] = cvtpk(v0[0], v0[1]); u[1] = cvtpk(v0[2], v0[3]);
                    u[2] = cvtpk(v1[0], v1[1]); u[3] = cvtpk(v1[2], v1[3]);
                    bq[z * 4 + fn] = __builtin_bit_cast(bhalf8, u);
                }
        }
    };

    float kcA[4], kcB[4], ksA[4], ksB[4], kC2[4];
    float xv[4];

    // ---- prologue: tile 0 loads + first x values ----
    loadB(bq0, 0);
#pragma unroll
    for (int fm = 0; fm < 4; ++fm) xv[fm] = xb[fm * 16 * IDIM];

#pragma unroll 1
    for (int ii = 0; ii < 16; ++ii) {
        // ================= even tile T=2ii (h=0): seed =================
        loadB(bq1, 2 * ii + 1);
#pragma unroll
        for (int fm = 0; fm < 4; ++fm) {
            float rev = xv[fm] * INV2PI;
            float a1 = __builtin_amdgcn_fractf(rev);
            float c1 = __builtin_amdgcn_cosf(a1);
            float s1 = __builtin_amdgcn_sinf(a1);
            float C2x = c1 + c1;
            float a0 = __builtin_amdgcn_fractf(rev * m0f);
            float c0 = __builtin_amdgcn_cosf(a0);
            float s0 = __builtin_amdgcn_sinf(a0);
            float cBv = __builtin_fmaf(c0, c1, -(s0 * s1));   // cos((m0+1)x)
            float sBv = __builtin_fmaf(s0, c1, c0 * s1);      // sin((m0+1)x)
            uvec4 uc, us;
            uc[0] = cvtpk(c0, cBv);
            us[0] = cvtpk(s0, sBv);
            {
                float A = c0, B = cBv;
                ADVP(A, B, C2x); uc[1] = cvtpk(A, B);
                ADVP(A, B, C2x); uc[2] = cvtpk(A, B);
                ADVP(A, B, C2x); uc[3] = cvtpk(A, B);
                kcA[fm] = A; kcB[fm] = B;
            }
            {
                float A = s0, B = sBv;
                ADVP(A, B, C2x); us[1] = cvtpk(A, B);
                ADVP(A, B, C2x); us[2] = cvtpk(A, B);
                ADVP(A, B, C2x); us[3] = cvtpk(A, B);
                ksA[fm] = A; ksB[fm] = B;
            }
            kC2[fm] = C2x;
            bhalf8 afc = __builtin_bit_cast(bhalf8, uc);
            bhalf8 afs = __builtin_bit_cast(bhalf8, us);
#pragma unroll
            for (int fn = 0; fn < 4; ++fn)
                acc[fm][fn] = __builtin_amdgcn_mfma_f32_16x16x32_bf16(
                    afc, bq0[fn], acc[fm][fn], 0, 0, 0);
#pragma unroll
            for (int fn = 0; fn < 4; ++fn)
                acc[fm][fn] = __builtin_amdgcn_mfma_f32_16x16x32_bf16(
                    afs, bq0[4 + fn], acc[fm][fn], 0, 0, 0);
        }

        // ================= odd tile T=2ii+1 (h=1): continue =================
        const bool more = (ii < 15);
        if (more) {
            loadB(bq0, 2 * ii + 2);
#pragma unroll
            for (int fm = 0; fm < 4; ++fm) xv[fm] = xb[fm * 16 * IDIM + ii + 1];
        }
#pragma unroll
        for (int fm = 0; fm < 4; ++fm) {
            float C2x = kC2[fm];
            uvec4 uc, us;
            {
                float A = kcA[fm], B = kcB[fm];
                ADVP(A, B, C2x); uc[0] = cvtpk(A, B);
                ADVP(A, B, C2x); uc[1] = cvtpk(A, B);
                ADVP(A, B, C2x); uc[2] = cvtpk(A, B);
                ADVP(A, B, C2x); uc[3] = cvtpk(A, B);
            }
            {
                float A = ksA[fm], B = ksB[fm];
                ADVP(A, B, C2x); us[0] = cvtpk(A, B);
                ADVP(A, B, C2x); us[1] = cvtpk(A, B);
                ADVP(A, B, C2x); us[2] = cvtpk(A, B);
                ADVP(A, B, C2x); us[3] = cvtpk(A, B);
            }
            bhalf8 afc = __builtin_bit_cast(bhalf8, uc);
            bhalf8 afs = __builtin_bit_cast(bhalf8, us);
#pragma unroll
            for (int fn = 0; fn < 4; ++fn)
                acc[fm][fn] = __builtin_amdgcn_mfma_f32_16x16x32_bf16(
                    afc, bq1[fn], acc[fm][fn], 0, 0, 0);
#pragma unroll
            for (int fn = 0; fn < 4; ++fn)
                acc[fm][fn] = __builtin_amdgcn_mfma_f32_16x16x32_bf16(
                    afs, bq1[4 + fn], acc[fm][fn], 0, 0, 0);
        }
    }

    // epilogue: C/D layout col=lane&15, row=(lane>>4)*4+r
#pragma unroll
    for (int fm = 0; fm < 4; ++fm) {
#pragma unroll
        for (int fn = 0; fn < 4; ++fn) {
            int col = col0 + wave_n * 64 + fn * 16 + (lane & 15);
#pragma unroll
            for (int r = 0; r < 4; ++r) {
                int row = row0 + wave_m * 64 + fm * 16 + ((lane >> 4) * 4) + r;
                atomicAdd(&out[(size_t)row * ODIM + col], acc[fm][fn][r]);
            }
        }
    }
}

extern "C" void kernel_launch(void* const* d_in, const int* in_sizes, int n_in,
                              void* d_out, int out_size, void* d_ws, size_t ws_size,
                              hipStream_t stream) {
    (void)in_sizes; (void)n_in; (void)out_size;
    const float* x      = (const float*)d_in[0];
    const float* coeffs = (const float*)d_in[1];
    const float* bias   = (const float*)d_in[2];
    float* out = (float*)d_out;

    const bool use_ws = (ws_size >= WS_NEED) && (((uintptr_t)d_ws & 15) == 0);

    bias_init<<<dim3(2048), dim3(256), 0, stream>>>(bias, out);
    if (use_ws) {
        prep_b<<<dim3(512), dim3(512), 0, stream>>>(coeffs, (short*)d_ws);
        fkan_gemm<1><<<dim3(2048), dim3(256), 0, stream>>>(x, coeffs, (const short*)d_ws, out);
    } else {
        fkan_gemm<0><<<dim3(2048), dim3(256), 0, stream>>>(x, coeffs, nullptr, out);
    }
}